// Round 6
// baseline (166.669 us; speedup 1.0000x reference)
//
#include <hip/hip_runtime.h>
#include <hip/hip_bf16.h>

// Problem constants
#define Bc   128
#define Nc   16
#define Fc   20
#define Dc   4
#define Ec   256
#define Hc   128
#define NBc  10
#define BNc  (Bc*Nc)          // 2048
#define Mrows (BNc*Fc)        // 40960

#define NG   128              // row-groups of 16 rows

typedef __attribute__((ext_vector_type(8))) short short8;
typedef __attribute__((ext_vector_type(4))) float f32x4;

static __device__ __forceinline__ unsigned short f2bf(float f) {
    union { float f; unsigned u; } v; v.f = f;
    unsigned r = v.u + 0x7fff + ((v.u >> 16) & 1);   // RNE
    return (unsigned short)(r >> 16);
}
static __device__ __forceinline__ float bf2f(unsigned u16) {
    union { unsigned u; float f; } v; v.u = u16 << 16; return v.f;
}
static __device__ __forceinline__ float bfhi2f(unsigned u) {
    union { unsigned uu; float f; } v; v.uu = u & 0xffff0000u; return v.f;
}
static __device__ __forceinline__ float fast_tanh(float v) {
    float t = __expf(2.f * v);
    return 1.f - 2.f * __builtin_amdgcn_rcpf(t + 1.f);
}
static __device__ __forceinline__ float fast_sigmoid(float v) {
    return __builtin_amdgcn_rcpf(1.f + __expf(-v));
}

// ---------------------------------------------------------------------------
// K0: transpose + bf16-convert a weight matrix  w[256][768] -> wT[768][256]
// ---------------------------------------------------------------------------
__global__ __launch_bounds__(256)
void k_wprep(const float* __restrict__ w, unsigned short* __restrict__ wT) {
    int n = blockIdx.x;        // 0..767
    int k = threadIdx.x;       // 0..255
    wT[n * 256 + k] = f2bf(w[k * 768 + n]);
}

// ---------------------------------------------------------------------------
// Shared geometry:
//  block = 1024 thr = 16 waves; wave w owns e in [w*16,(w+1)*16);
//  3 gate-col tiles per wave: col(t) = t*256 + w*16 + lr.
//  w_ih B-fragments: kk 0..5 in VGPRs, kk 6..7 in LDS (96 KB).
//  C layout: col = lr, row = lg*4 + j.
//  gi stored bf16 in fragment order: [f][g][w][t][lane][4].
// ---------------------------------------------------------------------------
#define WL_IDX(w, t, kkr, l) (((((w) * 3 + (t)) * 2 + (kkr)) * 64 + (l)) * 8)

// ---------------------------------------------------------------------------
// K1: fused feature-build + input-projection.
// Grid (128 b, 2 f-halves); block covers b's 16 rows for 10 f values.
// Per f: P1 pairwise diff/dist (+idx load) -> P2 prop+rel (all lanes busy)
//        -> P3 +bemb, pack bf16 x-tile -> P4 MFMA with resident w_ih.
// Diagonal j==i handled by subtracting tanh(br) (diff=0, dist=sqrt(0)=0
// makes the diag term exactly tanh(br), bitwise-cancelled).
// ---------------------------------------------------------------------------
__global__ __launch_bounds__(1024, 4)
void k_build_gi(const float* __restrict__ ent, const int* __restrict__ bfeat,
                const float* __restrict__ Wp, const float* __restrict__ bp,
                const float* __restrict__ Wr, const float* __restrict__ br,
                const float* __restrict__ emb,
                const unsigned short* __restrict__ wihT,
                const float* __restrict__ bih,
                unsigned short* __restrict__ gi) {
    __shared__ __align__(16) unsigned short wl[16 * 3 * 2 * 64 * 8];  // 96 KB
    __shared__ __align__(16) float sDiff[16][16][4];                  // 4 KB
    __shared__ float sDist[16][16];                                   // 1 KB
    __shared__ int   sIdx[160];
    __shared__ float sC[11 * 128];                                    // Wp|bp|Wr|br
    __shared__ __align__(16) float xtf[16 * 256];                     // 16 KB
    __shared__ __align__(16) unsigned short xt[16 * 256];             // 8 KB (swizzled)

    const int b = blockIdx.x, fh = blockIdx.y;
    const int t = threadIdx.x;
    const int w = t >> 6, l = t & 63;
    const int lr = l & 15, lg = l >> 4;

    // resident w_ih fragments + folded bias
    short8 wr[3][6];
    float  bv[3];
    #pragma unroll
    for (int g3 = 0; g3 < 3; ++g3) {
        const unsigned short* wp = wihT + (size_t)(g3 * 256 + w * 16 + lr) * 256 + lg * 8;
        #pragma unroll
        for (int kk = 0; kk < 6; ++kk) wr[g3][kk] = *(const short8*)(wp + kk * 32);
        #pragma unroll
        for (int kk = 6; kk < 8; ++kk)
            *(short8*)&wl[WL_IDX(w, g3, kk - 6, l)] = *(const short8*)(wp + kk * 32);
        bv[g3] = bih[g3 * 256 + w * 16 + lr];
    }
    // small const tables -> LDS
    for (int s = t; s < 11 * 128; s += 1024) {
        int row = s >> 7, hh = s & 127;
        float v;
        if (row < 4)       v = Wp[row * 128 + hh];
        else if (row == 4) v = bp[hh];
        else if (row < 10) v = Wr[(row - 5) * 128 + hh];
        else               v = br[hh];
        sC[s] = v;
    }
    const int h  = t & 127;
    const int i0 = t >> 7;           // rows i0 and i0+8
    __syncthreads();

    const float tbr = fast_tanh(sC[10 * 128 + h]);

    for (int fi = 0; fi < 10; ++fi) {
        const int f = fh * 10 + fi;

        // P1: pairwise diff/dist + bemb indices
        if (t < 256) {
            int i = t >> 4, j = t & 15;
            float4 ei = *(const float4*)(ent + (size_t)((b * 16 + i) * 20 + f) * 4);
            float4 ej = *(const float4*)(ent + (size_t)((b * 16 + j) * 20 + f) * 4);
            float d0 = ei.x - ej.x, d1 = ei.y - ej.y;
            float d2 = ei.z - ej.z, d3 = ei.w - ej.w;
            sDiff[i][j][0] = d0; sDiff[i][j][1] = d1;
            sDiff[i][j][2] = d2; sDiff[i][j][3] = d3;
            sDist[i][j] = sqrtf(d0 * d0 + d1 * d1);   // dims 0,1 only (reference)
        } else if (t < 416) {
            int tt = t - 256;                          // 0..159
            int i = tt / 10, k = tt - i * 10;
            sIdx[tt] = bfeat[(size_t)((b * 16 + i) * 20 + f) * 10 + k];
        }
        __syncthreads();

        // P2: prop + rel, every lane does 2 rows
        {
            float w0 = sC[5 * 128 + h], w1 = sC[6 * 128 + h], w2 = sC[7 * 128 + h],
                  w3 = sC[8 * 128 + h], w4 = sC[9 * 128 + h], brr = sC[10 * 128 + h];
            float p0 = sC[0 * 128 + h], p1 = sC[1 * 128 + h], p2 = sC[2 * 128 + h],
                  p3 = sC[3 * 128 + h], bpp = sC[4 * 128 + h];
            #pragma unroll
            for (int rep = 0; rep < 2; ++rep) {
                int i = i0 + rep * 8;
                float4 ev = *(const float4*)(ent + (size_t)((b * 16 + i) * 20 + f) * 4);
                float pv = bpp;
                pv = fmaf(ev.x, p0, pv); pv = fmaf(ev.y, p1, pv);
                pv = fmaf(ev.z, p2, pv); pv = fmaf(ev.w, p3, pv);
                float s = 0.f;
                #pragma unroll
                for (int j = 0; j < 16; ++j) {
                    float v = brr;
                    v = fmaf(sDiff[i][j][0], w0, v);
                    v = fmaf(sDiff[i][j][1], w1, v);
                    v = fmaf(sDiff[i][j][2], w2, v);
                    v = fmaf(sDiff[i][j][3], w3, v);
                    v = fmaf(sDist[i][j],    w4, v);
                    s += fast_tanh(v);
                }
                xtf[i * 256 + h]       = fast_tanh(pv);
                xtf[i * 256 + 128 + h] = s - tbr;      // diagonal cancelled exactly
            }
        }
        __syncthreads();

        // P3: + binary-feature embeddings, pack to swizzled bf16 x-tile
        {
            int i  = t >> 6;                // == wave id, sIdx reads wave-uniform
            int e4 = l * 4;
            f32x4 q = *(const f32x4*)&xtf[i * 256 + e4];
            #pragma unroll
            for (int k = 0; k < 10; ++k) {
                int idx = sIdx[i * 10 + k];
                float4 evv = *(const float4*)(emb + (size_t)idx * 256 + e4);
                q[0] += evv.x; q[1] += evv.y; q[2] += evv.z; q[3] += evv.w;
            }
            uint2 o;
            o.x = (unsigned)f2bf(q[0]) | ((unsigned)f2bf(q[1]) << 16);
            o.y = (unsigned)f2bf(q[2]) | ((unsigned)f2bf(q[3]) << 16);
            *(uint2*)((char*)xt + ((i * 512 + e4 * 2) ^ ((i & 7) << 4))) = o;
        }
        __syncthreads();

        // P4: MFMA x-tile @ w_ih -> gi fragments (bias folded)
        f32x4 acc[3] = {};
        #pragma unroll
        for (int kk = 0; kk < 8; ++kk) {
            int bo = (lr * 512 + kk * 64 + lg * 16) ^ ((lr & 7) << 4);
            short8 a = *(const short8*)((const char*)xt + bo);
            short8 b0, b1, b2;
            if (kk < 6) { b0 = wr[0][kk]; b1 = wr[1][kk]; b2 = wr[2][kk]; }
            else {
                b0 = *(const short8*)&wl[WL_IDX(w, 0, kk - 6, l)];
                b1 = *(const short8*)&wl[WL_IDX(w, 1, kk - 6, l)];
                b2 = *(const short8*)&wl[WL_IDX(w, 2, kk - 6, l)];
            }
            acc[0] = __builtin_amdgcn_mfma_f32_16x16x32_bf16(a, b0, acc[0], 0, 0, 0);
            acc[1] = __builtin_amdgcn_mfma_f32_16x16x32_bf16(a, b1, acc[1], 0, 0, 0);
            acc[2] = __builtin_amdgcn_mfma_f32_16x16x32_bf16(a, b2, acc[2], 0, 0, 0);
        }
        #pragma unroll
        for (int g3 = 0; g3 < 3; ++g3) {
            uint2 o;
            o.x = (unsigned)f2bf(acc[g3][0] + bv[g3]) | ((unsigned)f2bf(acc[g3][1] + bv[g3]) << 16);
            o.y = (unsigned)f2bf(acc[g3][2] + bv[g3]) | ((unsigned)f2bf(acc[g3][3] + bv[g3]) << 16);
            size_t idx = ((((size_t)f * NG + b) * 48) + w * 3 + g3) * 256 + l * 4;
            *(uint2*)(gi + idx) = o;
        }
        // next-iteration barriers order the xt/sDiff reuse — no extra barrier
    }
}

// ---------------------------------------------------------------------------
// K3: fused GRU, weights resident (unchanged from R5). Grid NG.
// ---------------------------------------------------------------------------
__global__ __launch_bounds__(1024, 4)
void k_gru(const unsigned short* __restrict__ gi,
           const unsigned short* __restrict__ whhT,
           const float* __restrict__ bhh,
           float* __restrict__ out) {
    __shared__ __align__(16) unsigned short hb[2][16 * 256];          // 16 KB, XOR-swizzled
    __shared__ __align__(16) unsigned short wl[16 * 3 * 2 * 64 * 8];  // 96 KB
    int g = blockIdx.x;
    int w = threadIdx.x >> 6, l = threadIdx.x & 63;
    int lr = l & 15, lg = l >> 4;
    int bn0 = g * 16;

    for (int t = threadIdx.x; t < 16 * 256; t += 1024) hb[0][t] = 0;

    short8 wr[3][6];
    #pragma unroll
    for (int t = 0; t < 3; ++t) {
        const unsigned short* wp = whhT + (size_t)(t * 256 + w * 16 + lr) * 256 + lg * 8;
        #pragma unroll
        for (int kk = 0; kk < 6; ++kk) wr[t][kk] = *(const short8*)(wp + kk * 32);
        #pragma unroll
        for (int kk = 6; kk < 8; ++kk)
            *(short8*)&wl[WL_IDX(w, t, kk - 6, l)] = *(const short8*)(wp + kk * 32);
    }
    float bhR = bhh[w * 16 + lr];
    float bhZ = bhh[256 + w * 16 + lr];
    float bhN = bhh[512 + w * 16 + lr];
    __syncthreads();

    float hold[4] = {};
    const unsigned short* gp = gi + ((size_t)g * 48 + w * 3) * 256 + l * 4;
    const size_t fstr = (size_t)NG * 48 * 256;

    for (int f = 0; f < Fc; ++f) {
        uint2 gv0 = *(const uint2*)(gp);
        uint2 gv1 = *(const uint2*)(gp + 256);
        uint2 gv2 = *(const uint2*)(gp + 512);
        gp += fstr;

        const char* hbuf = (const char*)hb[f & 1];
        f32x4 acc[3] = {};
        #pragma unroll
        for (int kk = 0; kk < 8; ++kk) {
            int bo = (lr * 512 + kk * 64 + lg * 16) ^ ((lr & 7) << 4);
            short8 a = *(const short8*)(hbuf + bo);
            short8 b0, b1, b2;
            if (kk < 6) { b0 = wr[0][kk]; b1 = wr[1][kk]; b2 = wr[2][kk]; }
            else {
                b0 = *(const short8*)&wl[WL_IDX(w, 0, kk - 6, l)];
                b1 = *(const short8*)&wl[WL_IDX(w, 1, kk - 6, l)];
                b2 = *(const short8*)&wl[WL_IDX(w, 2, kk - 6, l)];
            }
            acc[0] = __builtin_amdgcn_mfma_f32_16x16x32_bf16(a, b0, acc[0], 0, 0, 0);
            acc[1] = __builtin_amdgcn_mfma_f32_16x16x32_bf16(a, b1, acc[1], 0, 0, 0);
            acc[2] = __builtin_amdgcn_mfma_f32_16x16x32_bf16(a, b2, acc[2], 0, 0, 0);
        }

        float giR[4] = { bf2f(gv0.x & 0xffffu), bfhi2f(gv0.x), bf2f(gv0.y & 0xffffu), bfhi2f(gv0.y) };
        float giZ[4] = { bf2f(gv1.x & 0xffffu), bfhi2f(gv1.x), bf2f(gv1.y & 0xffffu), bfhi2f(gv1.y) };
        float giN[4] = { bf2f(gv2.x & 0xffffu), bfhi2f(gv2.x), bf2f(gv2.y & 0xffffu), bfhi2f(gv2.y) };

        bool last = (f == Fc - 1);
        char* wbuf = (char*)hb[(f + 1) & 1];
        #pragma unroll
        for (int j = 0; j < 4; ++j) {
            float rg = fast_sigmoid(giR[j] + acc[0][j] + bhR);
            float zg = fast_sigmoid(giZ[j] + acc[1][j] + bhZ);
            float ng = fast_tanh(giN[j] + rg * (acc[2][j] + bhN));
            float h  = (1.f - zg) * ng + zg * hold[j];
            hold[j] = h;
            int row = lg * 4 + j;
            if (last) {
                out[(size_t)(bn0 + row) * Ec + w * 16 + lr] = h;
            } else {
                int bo = (row * 512 + (w * 16 + lr) * 2) ^ ((row & 7) << 4);
                *(unsigned short*)(wbuf + bo) = f2bf(h);
            }
        }
        if (!last) __syncthreads();
    }
}

// ---------------------------------------------------------------------------
extern "C" void kernel_launch(void* const* d_in, const int* in_sizes, int n_in,
                              void* d_out, int out_size, void* d_ws, size_t ws_size,
                              hipStream_t stream) {
    const float* ent  = (const float*)d_in[0];
    const int*   bfeat= (const int*)  d_in[1];
    const float* Wp   = (const float*)d_in[2];
    const float* bp   = (const float*)d_in[3];
    const float* Wr   = (const float*)d_in[4];
    const float* br   = (const float*)d_in[5];
    const float* emb  = (const float*)d_in[6];
    const float* wih  = (const float*)d_in[7];
    const float* bih  = (const float*)d_in[8];
    const float* whh  = (const float*)d_in[9];
    const float* bhh  = (const float*)d_in[10];
    float* out = (float*)d_out;

    char* ws = (char*)d_ws;
    unsigned short* gi   = (unsigned short*)ws;                          // 63 MB
    unsigned short* wihT = (unsigned short*)(ws + (size_t)Mrows * 768 * 2);
    unsigned short* whhT = wihT + (size_t)768 * 256;

    k_wprep<<<768, 256, 0, stream>>>(wih, wihT);
    k_wprep<<<768, 256, 0, stream>>>(whh, whhT);

    dim3 g1(NG, 2);
    k_build_gi<<<g1, 1024, 0, stream>>>(ent, bfeat, Wp, bp, Wr, br, emb,
                                        wihT, bih, gi);

    k_gru<<<NG, 1024, 0, stream>>>(gi, whhT, bhh, out);
}

// Round 7
// 139.064 us; speedup vs baseline: 1.1985x; 1.1985x over previous
//
#include <hip/hip_runtime.h>
#include <hip/hip_bf16.h>

// Problem constants
#define Bc   128
#define Nc   16
#define Fc   20
#define Dc   4
#define Ec   256
#define Hc   128
#define NBc  10
#define BNc  (Bc*Nc)          // 2048
#define Mrows (BNc*Fc)        // 40960

#define NG   128              // row-groups of 16 rows (GRU blocks)

typedef __attribute__((ext_vector_type(8))) short short8;
typedef __attribute__((ext_vector_type(4))) float f32x4;

static __device__ __forceinline__ unsigned short f2bf(float f) {
    union { float f; unsigned u; } v; v.f = f;
    unsigned r = v.u + 0x7fff + ((v.u >> 16) & 1);   // RNE
    return (unsigned short)(r >> 16);
}
static __device__ __forceinline__ float bf2f(unsigned u16) {
    union { unsigned u; float f; } v; v.u = u16 << 16; return v.f;
}
static __device__ __forceinline__ float bfhi2f(unsigned u) {
    union { unsigned uu; float f; } v; v.uu = u & 0xffff0000u; return v.f;
}
static __device__ __forceinline__ float fast_tanh(float v) {
    float t = __expf(2.f * v);
    return 1.f - 2.f * __builtin_amdgcn_rcpf(t + 1.f);
}
static __device__ __forceinline__ float fast_sigmoid(float v) {
    return __builtin_amdgcn_rcpf(1.f + __expf(-v));
}

// ---------------------------------------------------------------------------
// K0: transpose + bf16-convert a weight matrix  w[256][768] -> wT[768][256]
// ---------------------------------------------------------------------------
__global__ __launch_bounds__(256)
void k_wprep(const float* __restrict__ w, unsigned short* __restrict__ wT) {
    int n = blockIdx.x;        // 0..767
    int k = threadIdx.x;       // 0..255
    wT[n * 256 + k] = f2bf(w[k * 768 + n]);
}

// ---------------------------------------------------------------------------
// K1: feature build, all lanes busy. Grid (128 b, 10 fq); 2 f per block.
// Per f: P1 all 256 pairwise diff/dist (+idx load) -> P2 rel+prop, thread
// (h = t&127, rowhalf = t>>7) does 8 rows x 16 j (diagonal included, then
// tanh(br) subtracted -> exact cancellation, branch-free) -> P3 +bemb from
// LDS-staged emb, pack bf16, coalesced store to x[f][bn][e].
// ---------------------------------------------------------------------------
__global__ __launch_bounds__(256)
void k_build_x2(const float* __restrict__ ent, const int* __restrict__ bfeat,
                const float* __restrict__ Wp, const float* __restrict__ bp,
                const float* __restrict__ Wr, const float* __restrict__ br,
                const float* __restrict__ emb, unsigned short* __restrict__ x) {
    __shared__ float sEmb[20 * 256];                  // 20 KB
    __shared__ float sC[11 * 128];                    // Wp|bp|Wr|br
    __shared__ __align__(16) float sDiff[16][16][4];  // 4 KB
    __shared__ float sDist[16][16];                   // 1 KB
    __shared__ int   sIdx[160];
    __shared__ __align__(16) float xtf[16 * 256];     // 16 KB

    const int b = blockIdx.x, fq = blockIdx.y;
    const int t = threadIdx.x;

    for (int s = t; s < 20 * 256; s += 256) sEmb[s] = emb[s];
    for (int s = t; s < 11 * 128; s += 256) {
        int row = s >> 7, hh = s & 127;
        float v;
        if (row < 4)       v = Wp[row * 128 + hh];
        else if (row == 4) v = bp[hh];
        else if (row < 10) v = Wr[(row - 5) * 128 + hh];
        else               v = br[hh];
        sC[s] = v;
    }
    __syncthreads();

    const int h  = t & 127;
    const int rh = t >> 7;
    const float w0 = sC[5 * 128 + h], w1 = sC[6 * 128 + h], w2 = sC[7 * 128 + h],
                w3 = sC[8 * 128 + h], w4 = sC[9 * 128 + h], brr = sC[10 * 128 + h];
    const float p0 = sC[0 * 128 + h], p1 = sC[1 * 128 + h], p2 = sC[2 * 128 + h],
                p3 = sC[3 * 128 + h], bpp = sC[4 * 128 + h];
    const float tbr = fast_tanh(brr);

    for (int fi = 0; fi < 2; ++fi) {
        const int f = fq * 2 + fi;

        // P1: all 256 pairwise diff/dist
        {
            int i = t >> 4, j = t & 15;
            float4 ei = *(const float4*)(ent + ((size_t)(b * 16 + i) * 20 + f) * 4);
            float4 ej = *(const float4*)(ent + ((size_t)(b * 16 + j) * 20 + f) * 4);
            float d0 = ei.x - ej.x, d1 = ei.y - ej.y;
            float d2 = ei.z - ej.z, d3 = ei.w - ej.w;
            sDiff[i][j][0] = d0; sDiff[i][j][1] = d1;
            sDiff[i][j][2] = d2; sDiff[i][j][3] = d3;
            sDist[i][j] = sqrtf(d0 * d0 + d1 * d1);   // dims 0,1 only (reference)
        }
        if (t < 160) {
            int i = t / 10, k = t - i * 10;
            sIdx[t] = bfeat[((size_t)(b * 16 + i) * 20 + f) * 10 + k];
        }
        __syncthreads();

        // P2: rel + prop, thread covers 8 rows
        #pragma unroll
        for (int ri = 0; ri < 8; ++ri) {
            int i = rh * 8 + ri;
            float4 ev = *(const float4*)(ent + ((size_t)(b * 16 + i) * 20 + f) * 4);
            float pv = bpp;
            pv = fmaf(ev.x, p0, pv); pv = fmaf(ev.y, p1, pv);
            pv = fmaf(ev.z, p2, pv); pv = fmaf(ev.w, p3, pv);
            float s = 0.f;
            #pragma unroll
            for (int j = 0; j < 16; ++j) {
                float v = brr;
                v = fmaf(sDiff[i][j][0], w0, v);
                v = fmaf(sDiff[i][j][1], w1, v);
                v = fmaf(sDiff[i][j][2], w2, v);
                v = fmaf(sDiff[i][j][3], w3, v);
                v = fmaf(sDist[i][j],    w4, v);
                s += fast_tanh(v);
            }
            xtf[i * 256 + h]       = fast_tanh(pv);
            xtf[i * 256 + 128 + h] = s - tbr;         // diagonal cancelled exactly
        }
        __syncthreads();

        // P3: + bemb, pack, coalesced bf16 store
        #pragma unroll
        for (int p = 0; p < 4; ++p) {
            int i  = p * 4 + (t >> 6);                // wave-uniform row
            int e4 = (t & 63) * 4;
            f32x4 q = *(const f32x4*)&xtf[i * 256 + e4];
            #pragma unroll
            for (int k = 0; k < 10; ++k) {
                int idx = sIdx[i * 10 + k];
                f32x4 ev = *(const f32x4*)&sEmb[idx * 256 + e4];
                q[0] += ev[0]; q[1] += ev[1]; q[2] += ev[2]; q[3] += ev[3];
            }
            uint2 o;
            o.x = (unsigned)f2bf(q[0]) | ((unsigned)f2bf(q[1]) << 16);
            o.y = (unsigned)f2bf(q[2]) | ((unsigned)f2bf(q[3]) << 16);
            *(uint2*)(x + ((size_t)f * BNc + b * 16 + i) * 256 + e4) = o;
        }
        __syncthreads();   // protect sDiff/sIdx/xtf before next f
    }
}

// ---------------------------------------------------------------------------
// K2: gi = x @ w_ih + b_ih, fragment-layout bf16 output.
// Grid (640 row-blocks of 64, 3 gates); 256 thr = 4 waves.
// A-tile (64x256 bf16) in XOR-swizzled LDS; B streamed from L2 (no VGPR
// residency -> no spill). Wave w owns col-tiles [w*4, w*4+4) of the gate.
// acc[rt][ct] = 16 f32x4 = 64 VGPR; total ~115.
// ---------------------------------------------------------------------------
__global__ __launch_bounds__(256, 2)
void k_gi(const unsigned short* __restrict__ x,
          const unsigned short* __restrict__ wihT,
          const float* __restrict__ bih,
          unsigned short* __restrict__ gi) {
    __shared__ __align__(16) unsigned short at[64 * 256];   // 32 KB
    const int mb = blockIdx.x, gb = blockIdx.y;
    const int t = threadIdx.x;
    const int w = t >> 6, l = t & 63, lr = l & 15, lg = l >> 4;
    const int m0 = mb * 64;

    // cooperative swizzled A-tile load (fully coalesced 16 B/lane)
    {
        const char* src = (const char*)(x + (size_t)m0 * 256);
        #pragma unroll
        for (int p = 0; p < 8; ++p) {
            int c  = p * 256 + t;
            int rr = c >> 5, cc = c & 31;
            int bo = (rr * 512 + cc * 16) ^ ((rr & 7) << 4);
            *(short8*)((char*)at + bo) = *(const short8*)(src + rr * 512 + cc * 16);
        }
    }
    __syncthreads();

    f32x4 acc[4][4] = {};   // [rt][ct]
    #pragma unroll
    for (int kk = 0; kk < 8; ++kk) {
        short8 bfr[4];
        #pragma unroll
        for (int ct = 0; ct < 4; ++ct) {
            int col = gb * 256 + (w * 4 + ct) * 16 + lr;
            bfr[ct] = *(const short8*)(wihT + (size_t)col * 256 + kk * 32 + lg * 8);
        }
        #pragma unroll
        for (int rt = 0; rt < 4; ++rt) {
            int row = rt * 16 + lr;
            int bo  = (row * 512 + kk * 64 + lg * 16) ^ ((lr & 7) << 4);
            short8 a = *(const short8*)((const char*)at + bo);
            #pragma unroll
            for (int ct = 0; ct < 4; ++ct)
                acc[rt][ct] = __builtin_amdgcn_mfma_f32_16x16x32_bf16(a, bfr[ct], acc[rt][ct], 0, 0, 0);
        }
    }

    const int f   = m0 / BNc;       // 32 blocks per f, no straddle
    const int bn0 = m0 % BNc;
    #pragma unroll
    for (int rt = 0; rt < 4; ++rt) {
        int g = (bn0 >> 4) + rt;
        #pragma unroll
        for (int ct = 0; ct < 4; ++ct) {
            int wg  = w * 4 + ct;
            int col = gb * 256 + wg * 16 + lr;
            float bv = bih[col];
            uint2 o;
            o.x = (unsigned)f2bf(acc[rt][ct][0] + bv) | ((unsigned)f2bf(acc[rt][ct][1] + bv) << 16);
            o.y = (unsigned)f2bf(acc[rt][ct][2] + bv) | ((unsigned)f2bf(acc[rt][ct][3] + bv) << 16);
            size_t idx = ((((size_t)f * NG + g) * 48) + wg * 3 + gb) * 256 + l * 4;
            *(uint2*)(gi + idx) = o;
        }
    }
}

// ---------------------------------------------------------------------------
// Shared geometry for K3: block = 1024 thr = 16 waves; wave w owns e in
// [w*16,(w+1)*16); 3 gate-col tiles: col(t) = t*256 + w*16 + lr.
// w_hh B-fragments: kk 0..5 in VGPRs, kk 6..7 in LDS (96 KB).
// amdgpu_waves_per_eu(4,4) raises the VGPR cap to 128 so wr[3][6] (72) fits.
// ---------------------------------------------------------------------------
#define WL_IDX(w, t, kkr, l) (((((w) * 3 + (t)) * 2 + (kkr)) * 64 + (l)) * 8)

__global__ __attribute__((amdgpu_flat_work_group_size(1024, 1024), amdgpu_waves_per_eu(4, 4)))
void k_gru(const unsigned short* __restrict__ gi,
           const unsigned short* __restrict__ whhT,
           const float* __restrict__ bhh,
           float* __restrict__ out) {
    __shared__ __align__(16) unsigned short hb[2][16 * 256];          // 16 KB, XOR-swizzled
    __shared__ __align__(16) unsigned short wl[16 * 3 * 2 * 64 * 8];  // 96 KB
    int g = blockIdx.x;
    int w = threadIdx.x >> 6, l = threadIdx.x & 63;
    int lr = l & 15, lg = l >> 4;
    int bn0 = g * 16;

    for (int t = threadIdx.x; t < 16 * 256; t += 1024) hb[0][t] = 0;

    short8 wr[3][6];
    #pragma unroll
    for (int t = 0; t < 3; ++t) {
        const unsigned short* wp = whhT + (size_t)(t * 256 + w * 16 + lr) * 256 + lg * 8;
        #pragma unroll
        for (int kk = 0; kk < 6; ++kk) wr[t][kk] = *(const short8*)(wp + kk * 32);
        #pragma unroll
        for (int kk = 6; kk < 8; ++kk)
            *(short8*)&wl[WL_IDX(w, t, kk - 6, l)] = *(const short8*)(wp + kk * 32);
    }
    float bhR = bhh[w * 16 + lr];
    float bhZ = bhh[256 + w * 16 + lr];
    float bhN = bhh[512 + w * 16 + lr];
    __syncthreads();

    float hold[4] = {};
    const unsigned short* gp = gi + ((size_t)g * 48 + w * 3) * 256 + l * 4;
    const size_t fstr = (size_t)NG * 48 * 256;

    for (int f = 0; f < Fc; ++f) {
        uint2 gv0 = *(const uint2*)(gp);
        uint2 gv1 = *(const uint2*)(gp + 256);
        uint2 gv2 = *(const uint2*)(gp + 512);
        gp += fstr;

        const char* hbuf = (const char*)hb[f & 1];
        f32x4 acc[3] = {};
        #pragma unroll
        for (int kk = 0; kk < 8; ++kk) {
            int bo = (lr * 512 + kk * 64 + lg * 16) ^ ((lr & 7) << 4);
            short8 a = *(const short8*)(hbuf + bo);
            short8 b0, b1, b2;
            if (kk < 6) { b0 = wr[0][kk]; b1 = wr[1][kk]; b2 = wr[2][kk]; }
            else {
                b0 = *(const short8*)&wl[WL_IDX(w, 0, kk - 6, l)];
                b1 = *(const short8*)&wl[WL_IDX(w, 1, kk - 6, l)];
                b2 = *(const short8*)&wl[WL_IDX(w, 2, kk - 6, l)];
            }
            acc[0] = __builtin_amdgcn_mfma_f32_16x16x32_bf16(a, b0, acc[0], 0, 0, 0);
            acc[1] = __builtin_amdgcn_mfma_f32_16x16x32_bf16(a, b1, acc[1], 0, 0, 0);
            acc[2] = __builtin_amdgcn_mfma_f32_16x16x32_bf16(a, b2, acc[2], 0, 0, 0);
        }

        float giR[4] = { bf2f(gv0.x & 0xffffu), bfhi2f(gv0.x), bf2f(gv0.y & 0xffffu), bfhi2f(gv0.y) };
        float giZ[4] = { bf2f(gv1.x & 0xffffu), bfhi2f(gv1.x), bf2f(gv1.y & 0xffffu), bfhi2f(gv1.y) };
        float giN[4] = { bf2f(gv2.x & 0xffffu), bfhi2f(gv2.x), bf2f(gv2.y & 0xffffu), bfhi2f(gv2.y) };

        bool last = (f == Fc - 1);
        char* wbuf = (char*)hb[(f + 1) & 1];
        #pragma unroll
        for (int j = 0; j < 4; ++j) {
            float rg = fast_sigmoid(giR[j] + acc[0][j] + bhR);
            float zg = fast_sigmoid(giZ[j] + acc[1][j] + bhZ);
            float ng = fast_tanh(giN[j] + rg * (acc[2][j] + bhN));
            float h  = (1.f - zg) * ng + zg * hold[j];
            hold[j] = h;
            int row = lg * 4 + j;
            if (last) {
                out[(size_t)(bn0 + row) * Ec + w * 16 + lr] = h;
            } else {
                int bo = (row * 512 + (w * 16 + lr) * 2) ^ ((row & 7) << 4);
                *(unsigned short*)(wbuf + bo) = f2bf(h);
            }
        }
        if (!last) __syncthreads();
    }
}

// ---------------------------------------------------------------------------
extern "C" void kernel_launch(void* const* d_in, const int* in_sizes, int n_in,
                              void* d_out, int out_size, void* d_ws, size_t ws_size,
                              hipStream_t stream) {
    const float* ent  = (const float*)d_in[0];
    const int*   bfeat= (const int*)  d_in[1];
    const float* Wp   = (const float*)d_in[2];
    const float* bp   = (const float*)d_in[3];
    const float* Wr   = (const float*)d_in[4];
    const float* br   = (const float*)d_in[5];
    const float* emb  = (const float*)d_in[6];
    const float* wih  = (const float*)d_in[7];
    const float* bih  = (const float*)d_in[8];
    const float* whh  = (const float*)d_in[9];
    const float* bhh  = (const float*)d_in[10];
    float* out = (float*)d_out;

    char* ws = (char*)d_ws;
    unsigned short* x    = (unsigned short*)ws;                           // 21 MB
    unsigned short* gi   = (unsigned short*)(ws + (size_t)Mrows * Ec * 2);// 63 MB
    unsigned short* wihT = (unsigned short*)(ws + (size_t)Mrows * Ec * 2
                                                + (size_t)Mrows * 768 * 2);
    unsigned short* whhT = wihT + (size_t)768 * 256;

    k_wprep<<<768, 256, 0, stream>>>(wih, wihT);
    k_wprep<<<768, 256, 0, stream>>>(whh, whhT);

    dim3 gx(Bc, 10);
    k_build_x2<<<gx, 256, 0, stream>>>(ent, bfeat, Wp, bp, Wr, br, emb, x);

    dim3 gg(Mrows / 64, 3);
    k_gi<<<gg, 256, 0, stream>>>(x, wihT, bih, gi);

    k_gru<<<NG, 1024, 0, stream>>>(gi, whhT, bhh, out);
}